// Round 1
// baseline (272.619 us; speedup 1.0000x reference)
//
#include <hip/hip_runtime.h>

// PseudoImageScatter: (4,12000,64) fp32 features + (4,12000,4) int coords
// -> (4,64,496,496) fp32 grid, last-write-wins on duplicate (y,x).
//
// Pass 1: winner[b][y][x] = max pillar index p that maps to the cell (atomicMax,
//         init -1). Matches numpy's sequential last-write-wins semantics.
// Pass 2: gather — every output element reads its cell's winner and either the
//         winning pillar's feature or 0. Fully coalesced float4 stores cover the
//         mandatory 252 MB output write; no separate zeroing pass, no scattered
//         partial-line writes.

constexpr int B = 4, P = 12000, Fdim = 64, H = 496, W = 496;
constexpr int W4 = W / 4;                 // 124 float4 per row
constexpr int NCELL = B * H * W;          // 984064 cells -> 3.94 MB winner map in d_ws
constexpr int NPILLAR = B * P;            // 48000
constexpr int TOTAL4 = B * Fdim * H * W4; // 15,745,024 float4 outputs

__global__ void init_winner_kernel(int* __restrict__ winner) {
    int i = blockIdx.x * blockDim.x + threadIdx.x;
    constexpr int N4 = NCELL / 4;         // 246016, exactly 961 blocks * 256
    if (i < N4)
        reinterpret_cast<int4*>(winner)[i] = make_int4(-1, -1, -1, -1);
}

__global__ void scatter_winner_kernel(const int* __restrict__ coords,
                                      int* __restrict__ winner) {
    int i = blockIdx.x * blockDim.x + threadIdx.x;
    if (i >= NPILLAR) return;
    int b = i / P;
    int p = i - b * P;
    const int* c = coords + i * 4;        // (b,p,4): [?, y, x, ?]
    int y = c[1];
    int x = c[2];
    // invalid coords are routed to the sliced-off column in the reference -> skip
    if ((unsigned)y < (unsigned)H && (unsigned)x < (unsigned)W)
        atomicMax(&winner[(b * H + y) * W + x], p);
}

__global__ void gather_kernel(const float* __restrict__ feat,
                              const int* __restrict__ winner,
                              float4* __restrict__ out) {
    int idx = blockIdx.x * blockDim.x + threadIdx.x;
    if (idx >= TOTAL4) return;
    // idx = ((b*64 + f)*496 + y)*124 + x4  -- identical linearization to output
    int x4 = idx % W4;
    int t  = idx / W4;
    int y  = t % H;
    int t2 = t / H;
    int f  = t2 & (Fdim - 1);
    int b  = t2 >> 6;

    int cell = (b * H + y) * W + x4 * 4;  // row start 1984 B -> 16B-aligned
    int4 w = *reinterpret_cast<const int4*>(winner + cell);

    float4 v = make_float4(0.f, 0.f, 0.f, 0.f);
    int base = b * P * Fdim + f;          // feat[(b*P + w)*64 + f]
    if (w.x >= 0) v.x = feat[base + w.x * Fdim];
    if (w.y >= 0) v.y = feat[base + w.y * Fdim];
    if (w.z >= 0) v.z = feat[base + w.z * Fdim];
    if (w.w >= 0) v.w = feat[base + w.w * Fdim];
    out[idx] = v;
}

extern "C" void kernel_launch(void* const* d_in, const int* in_sizes, int n_in,
                              void* d_out, int out_size, void* d_ws, size_t ws_size,
                              hipStream_t stream) {
    const float* feat  = (const float*)d_in[0];
    const int* coords  = (const int*)d_in[1];   // harness passes integer inputs as int32
    float4* out        = (float4*)d_out;
    int* winner        = (int*)d_ws;            // needs 3.94 MB scratch

    init_winner_kernel<<<(NCELL / 4 + 255) / 256, 256, 0, stream>>>(winner);
    scatter_winner_kernel<<<(NPILLAR + 255) / 256, 256, 0, stream>>>(coords, winner);
    gather_kernel<<<(TOTAL4 + 255) / 256, 256, 0, stream>>>(feat, winner, out);
}

// Round 2
// 260.402 us; speedup vs baseline: 1.0469x; 1.0469x over previous
//
#include <hip/hip_runtime.h>

// PseudoImageScatter: (4,12000,64) fp32 features + (4,12000,4) int coords
// -> (4,64,496,496) fp32 grid, last-write-wins on duplicate (y,x).
//
// Pass 0: hipMemsetAsync winner map to 0xFF (-1 per int) — graph-capturable.
// Pass 1: winner[b][y][x] = atomicMax of pillar index (numpy last-write-wins).
// Pass 2: gather, ONE THREAD PER CELL-GROUP (int4 of winners): read winner
//         once, stream each winning pillar's 256 B feature row via float4
//         loads, transpose in registers, and emit 64 coalesced float4 stores
//         (one per channel plane). Winner traffic 3.9 MB (was 252 MB of L2
//         re-reads), feat rows read exactly once (12 MB), stores = mandatory
//         252 MB.

constexpr int B = 4, P = 12000, Fdim = 64, H = 496, W = 496;
constexpr int W4 = W / 4;                 // 124 float4 per row
constexpr int NCELL = B * H * W;          // 984064 -> 3.94 MB winner map in d_ws
constexpr int NPILLAR = B * P;            // 48000
constexpr int PLANE4 = H * W4;            // 61504 float4 per (b,f) plane
constexpr int NGROUP = B * PLANE4;        // 246016 cell-groups; 64 | 61504 so
                                          // waves never straddle a batch edge

__global__ void scatter_winner_kernel(const int* __restrict__ coords,
                                      int* __restrict__ winner) {
    int i = blockIdx.x * blockDim.x + threadIdx.x;
    if (i >= NPILLAR) return;
    int b = i / P;
    int p = i - b * P;
    const int* c = coords + (size_t)i * 4;  // (b,p,4): [?, y, x, ?]
    int y = c[1];
    int x = c[2];
    // invalid coords land in the sliced-off column of the reference -> skip
    if ((unsigned)y < (unsigned)H && (unsigned)x < (unsigned)W)
        atomicMax(&winner[(b * H + y) * W + x], p);
}

__global__ void __launch_bounds__(256)
gather_kernel(const float* __restrict__ feat,
              const int* __restrict__ winner,
              float4* __restrict__ out) {
    int g = blockIdx.x * blockDim.x + threadIdx.x;
    if (g >= NGROUP) return;

    int4 w = reinterpret_cast<const int4*>(winner)[g];

    int b = g / PLANE4;
    int r = g - b * PLANE4;                 // y*W4 + x4 within the plane
    float4* op = out + (size_t)b * Fdim * PLANE4 + r;

    // clamped base pointers are always in-bounds; loads are exec-masked below
    const float4* p0 = reinterpret_cast<const float4*>(feat + ((size_t)b * P + max(w.x, 0)) * Fdim);
    const float4* p1 = reinterpret_cast<const float4*>(feat + ((size_t)b * P + max(w.y, 0)) * Fdim);
    const float4* p2 = reinterpret_cast<const float4*>(feat + ((size_t)b * P + max(w.z, 0)) * Fdim);
    const float4* p3 = reinterpret_cast<const float4*>(feat + ((size_t)b * P + max(w.w, 0)) * Fdim);
    const float4 z4 = make_float4(0.f, 0.f, 0.f, 0.f);

#pragma unroll 4
    for (int c = 0; c < Fdim / 4; ++c) {    // 16 chunks of 4 channels
        float4 a0 = z4, a1 = z4, a2 = z4, a3 = z4;
        if (w.x >= 0) a0 = p0[c];
        if (w.y >= 0) a1 = p1[c];
        if (w.z >= 0) a2 = p2[c];
        if (w.w >= 0) a3 = p3[c];
        // register transpose: channel f = 4c+j takes component j of each cell
        op[(4 * c + 0) * PLANE4] = make_float4(a0.x, a1.x, a2.x, a3.x);
        op[(4 * c + 1) * PLANE4] = make_float4(a0.y, a1.y, a2.y, a3.y);
        op[(4 * c + 2) * PLANE4] = make_float4(a0.z, a1.z, a2.z, a3.z);
        op[(4 * c + 3) * PLANE4] = make_float4(a0.w, a1.w, a2.w, a3.w);
    }
}

extern "C" void kernel_launch(void* const* d_in, const int* in_sizes, int n_in,
                              void* d_out, int out_size, void* d_ws, size_t ws_size,
                              hipStream_t stream) {
    const float* feat = (const float*)d_in[0];
    const int* coords = (const int*)d_in[1];   // integer inputs arrive as int32
    int* winner       = (int*)d_ws;            // 3.94 MB scratch

    // 0xFF bytes == -1 as int32: "empty" marker
    hipMemsetAsync(winner, 0xFF, (size_t)NCELL * sizeof(int), stream);
    scatter_winner_kernel<<<(NPILLAR + 255) / 256, 256, 0, stream>>>(coords, winner);
    gather_kernel<<<(NGROUP + 255) / 256, 256, 0, stream>>>(feat, winner, (float4*)d_out);
}